// Round 2
// baseline (185.311 us; speedup 1.0000x reference)
//
#include <hip/hip_runtime.h>
#include <math.h>

#define BB 128
#define LL 512
#define KK 8
#define DD 300
#define D4 75            // D in fp16-quad (8B) units: 300 = 75*4
#define CC 14
#define STREAMS 4
#define L_PER_STREAM 4
#define L_PER_BLOCK 16   // STREAMS * L_PER_STREAM
#define NUM_LC (LL / L_PER_BLOCK)   // 32 partials per b

#define R_F4_ELEMS ((4905 * 300) / 4)   // 367875

typedef _Float16 h2 __attribute__((ext_vector_type(2)));
typedef _Float16 h4 __attribute__((ext_vector_type(4)));
typedef float    f4 __attribute__((ext_vector_type(4)));

// prep: convert R fp32 -> fp16 table (2.94 MB, per-XCD-L2-resident).
__global__ __launch_bounds__(256) void prep(
    const f4* __restrict__ R4, h4* __restrict__ R16)
{
    const int i = blockIdx.x * 256 + threadIdx.x;
    if (i < R_F4_ELEMS) {
        const f4 f = __builtin_nontemporal_load(R4 + i);
        h4 o;
        o.x = (_Float16)f.x; o.y = (_Float16)f.y;
        o.z = (_Float16)f.z; o.w = (_Float16)f.w;
        R16[i] = o;
    }
}

// Block = 16 l's, 320 threads = 4 streams x 75 lanes. 4096 blocks (2x round 1)
// for latency hiding. Per stream: ALL 36 dwordx2 R16 gathers (4 l's x 9 rows)
// issued back-to-back before any compute -> ~36 loads in flight per wave.
// E values + gates are re-read from LDS at use time (wave-broadcast, free)
// so they don't occupy VGPRs across the gather window.
__global__ __launch_bounds__(320, 2) void gnn_agg(
    const int* __restrict__ master, const int* __restrict__ slaves,
    const int* __restrict__ edges, const float* __restrict__ E,
    const float* __restrict__ N, const h4* __restrict__ Rv,
    f4* __restrict__ Xp)
{
    const int b  = blockIdx.x;
    const int lc = blockIdx.y;
    const int t  = threadIdx.x;
    const int bl0 = b * LL + lc * L_PER_BLOCK;

    __shared__ int   olds[L_PER_BLOCK][9];      // [l][k]=slave off, [l][8]=master off
    __shared__ int   ebuf[L_PER_BLOCK * KK];    // packed h2(ev,ev)
    __shared__ float nnbuf[L_PER_BLOCK];
    __shared__ f4    sred[STREAMS][D4];         // cross-stream reduction

    if (t < L_PER_BLOCK * KK) {                 // 128 lanes: E gather + slave offs
        const int eidx = __builtin_nontemporal_load(edges + bl0 * KK + t);
        const _Float16 ev = (_Float16)__builtin_nontemporal_load(E + eidx);
        h2 p; p.x = ev; p.y = ev;
        ebuf[t] = __builtin_bit_cast(int, p);
        const int sn = __builtin_nontemporal_load(slaves + bl0 * KK + t);
        olds[t >> 3][t & 7] = sn * D4;
    } else if (t < L_PER_BLOCK * KK + L_PER_BLOCK) {   // 16 lanes: master + gate
        const int l = t - L_PER_BLOCK * KK;
        const int m = __builtin_nontemporal_load(master + bl0 + l);
        olds[l][8] = m * D4;
        nnbuf[l]   = N[m];
    }
    __syncthreads();

    const bool act = (t < STREAMS * D4);        // 300 active lanes
    const int  s   = act ? t / D4 : 0;
    const int  pos = t - s * D4;

    if (act) {
        const int ls0 = s * L_PER_STREAM;

        // ---- issue ALL gathers for this stream's 4 l's ----
        int off[L_PER_STREAM][9];
#pragma unroll
        for (int u = 0; u < L_PER_STREAM; ++u)
#pragma unroll
            for (int k = 0; k < 9; ++k) off[u][k] = olds[ls0 + u][k];

        h4 r[L_PER_STREAM][9];
#pragma unroll
        for (int u = 0; u < L_PER_STREAM; ++u)
#pragma unroll
            for (int k = 0; k < 9; ++k)
                r[u][k] = Rv[off[u][k] + pos];      // global_load_dwordx2 x36

        // ---- compute: E/gate re-read from LDS (broadcast) at use ----
        float a0 = 0.f, a1 = 0.f, a2 = 0.f, a3 = 0.f;
#pragma unroll
        for (int u = 0; u < L_PER_STREAM; ++u) {
            const int l = ls0 + u;
            h2 e2 = __builtin_bit_cast(h2, ebuf[l * KK]);
            h4 e4 = {e2.x, e2.y, e2.x, e2.y};
            h4 mx = r[u][0] * e4;
#pragma unroll
            for (int k = 1; k < KK; ++k) {
                h2 ek2 = __builtin_bit_cast(h2, ebuf[l * KK + k]);
                h4 ek  = {ek2.x, ek2.y, ek2.x, ek2.y};
                mx = __builtin_elementwise_max(mx, r[u][k] * ek);
            }
            const float n = nnbuf[l], g = 1.f - n;
            const h4 rm = r[u][8];
            a0 = fmaf(g, (float)mx.x, fmaf(n, (float)rm.x, a0));
            a1 = fmaf(g, (float)mx.y, fmaf(n, (float)rm.y, a1));
            a2 = fmaf(g, (float)mx.z, fmaf(n, (float)rm.z, a2));
            a3 = fmaf(g, (float)mx.w, fmaf(n, (float)rm.w, a3));
        }
        f4 v; v.x = a0; v.y = a1; v.z = a2; v.w = a3;
        sred[s][pos] = v;
    }
    __syncthreads();

    if (t < D4) {
        const f4 v0 = sred[0][t], v1 = sred[1][t], v2 = sred[2][t], v3 = sred[3][t];
        f4 v;
        v.x = (v0.x + v1.x) + (v2.x + v3.x);
        v.y = (v0.y + v1.y) + (v2.y + v3.y);
        v.z = (v0.z + v1.z) + (v2.z + v3.z);
        v.w = (v0.w + v1.w) + (v2.w + v3.w);
        __builtin_nontemporal_store(v, Xp + (lc * BB + b) * D4 + t);
    }
}

// Reduce 32 partials -> x[b,:], then FC (300->14) + ReLU + softmax.
__global__ __launch_bounds__(320) void fc_softmax(
    const f4* __restrict__ Xp, const float* __restrict__ W,
    const float* __restrict__ bias, float* __restrict__ out)
{
    const int b = blockIdx.x;
    const int t = threadIdx.x;
    __shared__ __align__(16) float sx[DD];
    __shared__ float h[CC];

    if (t < D4) {
        f4 a = {0.f, 0.f, 0.f, 0.f};
        const f4* p = Xp + b * D4 + t;
#pragma unroll
        for (int lc = 0; lc < NUM_LC; ++lc) {
            const f4 v = __builtin_nontemporal_load(p + lc * (BB * D4));
            a.x += v.x; a.y += v.y; a.z += v.z; a.w += v.w;
        }
        ((f4*)sx)[t] = a;
    }
    __syncthreads();

    const int c = t >> 4;
    const int j = t & 15;
    if (c < CC) {
        float acc = 0.f;
        const float* w = W + c * DD;
        for (int d = j; d < DD; d += 16) acc += sx[d] * w[d];
#pragma unroll
        for (int off = 8; off > 0; off >>= 1) acc += __shfl_down(acc, off, 16);
        if (j == 0) h[c] = fmaxf(acc + bias[c], 0.f);
    }
    __syncthreads();
    if (t < CC) {
        float mx = -INFINITY;
#pragma unroll
        for (int i = 0; i < CC; ++i) mx = fmaxf(mx, h[i]);
        float ssum = 0.f;
#pragma unroll
        for (int i = 0; i < CC; ++i) ssum += expf(h[i] - mx);
        out[b * CC + t] = expf(h[t] - mx) / ssum;
    }
}

extern "C" void kernel_launch(void* const* d_in, const int* in_sizes, int n_in,
                              void* d_out, int out_size, void* d_ws, size_t ws_size,
                              hipStream_t stream) {
    const int*   master = (const int*)d_in[0];
    const int*   slaves = (const int*)d_in[1];
    const int*   edges  = (const int*)d_in[2];
    const float* R      = (const float*)d_in[3];
    const float* E      = (const float*)d_in[4];
    const float* N      = (const float*)d_in[5];
    const float* W      = (const float*)d_in[6];
    const float* bias   = (const float*)d_in[7];
    float* out = (float*)d_out;

    // ws layout (bytes): R16 [2,943,104] | X_part [NUM_LC*BB*DD*4 = 4,915,200]
    char* ws  = (char*)d_ws;
    h4*   R16 = (h4*)ws;
    f4*   Xp  = (f4*)(ws + 2943104);

    prep<<<(R_F4_ELEMS + 255) / 256, 256, 0, stream>>>((const f4*)R, R16);

    dim3 grid(BB, NUM_LC);
    gnn_agg<<<grid, STREAMS * 80, 0, stream>>>(master, slaves, edges, E, N, R16, Xp);

    fc_softmax<<<BB, 320, 0, stream>>>(Xp, W, bias, out);
}